// Round 1
// baseline (36050.345 us; speedup 1.0000x reference)
//
#include <hip/hip_runtime.h>
#include <math.h>

#define N_NODES 10000
#define N_EDGES 100000
#define NB      64
#define EMB     100
#define H       2000
#define LAYERS  4

#define C1_OC 50
#define C1_L  666
#define C2_OC 100
#define C2_L  221
#define C3_OC 150
#define C3_L  73
#define LIN1_IN  10950
#define LIN1_OUT 500

// ---------------- embedding + pad ----------------
__global__ void embed_kernel(const int* __restrict__ tokens,
                             const float* __restrict__ table,
                             float* __restrict__ h) {
  int n = blockIdx.x;
  int tok = tokens[n];
  for (int j = threadIdx.x; j < H; j += 256)
    h[(size_t)n * H + j] = (j < EMB) ? table[tok * EMB + j] : 0.f;
}

// ---------------- CSR build ----------------
__global__ void hist_kernel(const int* __restrict__ dst, int* __restrict__ counts, int e) {
  int i = blockIdx.x * 256 + threadIdx.x;
  if (i < e) atomicAdd(&counts[dst[i]], 1);
}

__global__ void scan_kernel(const int* __restrict__ counts, int* __restrict__ row_off, int n) {
  __shared__ int sums[1024];
  int tid = threadIdx.x;
  const int CH = (n + 1023) / 1024;
  int start = tid * CH;
  int local = 0;
  for (int i = 0; i < CH; i++)
    if (start + i < n) local += counts[start + i];
  sums[tid] = local;
  __syncthreads();
  for (int off = 1; off < 1024; off <<= 1) {
    int v = (tid >= off) ? sums[tid - off] : 0;
    __syncthreads();
    sums[tid] += v;
    __syncthreads();
  }
  int run = (tid > 0) ? sums[tid - 1] : 0;
  for (int i = 0; i < CH; i++)
    if (start + i < n) { row_off[start + i] = run; run += counts[start + i]; }
  if (tid == 1023) row_off[n] = run;
}

__global__ void scatter_kernel(const int* __restrict__ src, const int* __restrict__ dst,
                               const int* __restrict__ row_off, int* __restrict__ cursor,
                               int* __restrict__ csr_src, int e) {
  int i = blockIdx.x * 256 + threadIdx.x;
  if (i < e) {
    int d = dst[i];
    int pos = atomicAdd(&cursor[d], 1);
    csr_src[row_off[d] + pos] = src[i];
  }
}

__global__ void starts_kernel(const int* __restrict__ batch, int* __restrict__ starts, int n) {
  int i = blockIdx.x * 256 + threadIdx.x;
  if (i >= n) return;
  int b = batch[i];
  int pb = (i == 0) ? -1 : batch[i - 1];
  if (b != pb)
    for (int x = pb + 1; x <= b; x++) starts[x] = i;
  if (i == n - 1)
    for (int x = b + 1; x <= NB; x++) starts[x] = n;
}

// ---------------- GEMM  C = A(MxK) @ B(KxN), all row-major ----------------
__global__ __launch_bounds__(256) void gemm_nn_kernel(
    const float* __restrict__ A, const float* __restrict__ B, float* __restrict__ C,
    int M, int N, int K) {
  __shared__ float As[16][64];
  __shared__ float Bs[16][64];
  const int tid = threadIdx.x;
  const int bm = blockIdx.y * 64;
  const int bn = blockIdx.x * 64;
  const int tx = tid & 15;
  const int ty = tid >> 4;
  const int arow = tid >> 2;
  const int acol = (tid & 3) * 4;
  const int brow = tid >> 4;
  const int bcol = (tid & 15) * 4;
  float acc[4][4] = {};
  for (int k0 = 0; k0 < K; k0 += 16) {
    float4 av = make_float4(0.f, 0.f, 0.f, 0.f);
    if (bm + arow < M)
      av = *(const float4*)(A + (size_t)(bm + arow) * K + (k0 + acol));
    As[acol + 0][arow] = av.x;
    As[acol + 1][arow] = av.y;
    As[acol + 2][arow] = av.z;
    As[acol + 3][arow] = av.w;
    float4 bv = make_float4(0.f, 0.f, 0.f, 0.f);
    if (bn + bcol < N)
      bv = *(const float4*)(B + (size_t)(k0 + brow) * N + (bn + bcol));
    *(float4*)&Bs[brow][bcol] = bv;
    __syncthreads();
#pragma unroll
    for (int kk = 0; kk < 16; kk++) {
      float4 a = *(const float4*)&As[kk][ty * 4];
      float4 b = *(const float4*)&Bs[kk][tx * 4];
      float ar[4] = {a.x, a.y, a.z, a.w};
      float br[4] = {b.x, b.y, b.z, b.w};
#pragma unroll
      for (int i = 0; i < 4; i++)
#pragma unroll
        for (int j = 0; j < 4; j++)
          acc[i][j] = fmaf(ar[i], br[j], acc[i][j]);
    }
    __syncthreads();
  }
#pragma unroll
  for (int i = 0; i < 4; i++) {
    int row = bm + ty * 4 + i;
    if (row < M && bn + tx * 4 < N) {
      float4 v = make_float4(acc[i][0], acc[i][1], acc[i][2], acc[i][3]);
      *(float4*)(C + (size_t)row * N + bn + tx * 4) = v;
    }
  }
}

// ---------------- edge aggregation: agg[n] = sum m[src] over CSR ----------------
__global__ void agg_kernel(const float* __restrict__ m, const int* __restrict__ row_off,
                           const int* __restrict__ csr_src, float* __restrict__ agg) {
  int n = blockIdx.x;
  int s = row_off[n], e = row_off[n + 1];
  int tid = threadIdx.x;
  const float4* m4 = (const float4*)m;
  float4* a4 = (float4*)agg;
  float4 acc0 = make_float4(0, 0, 0, 0), acc1 = make_float4(0, 0, 0, 0);
  int idx0 = tid, idx1 = tid + 256;
  __shared__ int s_src[256];
  for (int base = s; base < e; base += 256) {
    int cnt = min(256, e - base);
    __syncthreads();
    if (tid < cnt) s_src[tid] = csr_src[base + tid];
    __syncthreads();
    for (int p = 0; p < cnt; p++) {
      size_t roff = (size_t)s_src[p] * (H / 4);
      float4 v0 = m4[roff + idx0];
      acc0.x += v0.x; acc0.y += v0.y; acc0.z += v0.z; acc0.w += v0.w;
      if (idx1 < H / 4) {
        float4 v1 = m4[roff + idx1];
        acc1.x += v1.x; acc1.y += v1.y; acc1.z += v1.z; acc1.w += v1.w;
      }
    }
  }
  a4[(size_t)n * (H / 4) + idx0] = acc0;
  if (idx1 < H / 4) a4[(size_t)n * (H / 4) + idx1] = acc1;
}

// ---------------- fused GRU: 6 gate GEMMs (B^T) + elementwise ----------------
__global__ __launch_bounds__(256) void gru_fused_kernel(
    const float* __restrict__ agg, const float* __restrict__ hcur,
    const float* __restrict__ W_ih, const float* __restrict__ W_hh,
    const float* __restrict__ b_ih, const float* __restrict__ b_hh,
    float* __restrict__ hnew, int M) {
  __shared__ float Aa[16][64];
  __shared__ float Ah[16][64];
  __shared__ float Bs[6][16][32];
  const int tid = threadIdx.x;
  const int bm = blockIdx.y * 64;
  const int bn = blockIdx.x * 32;
  const int tx = tid & 15;
  const int ty = tid >> 4;
  const int arow = tid >> 2;
  const int acol = (tid & 3) * 4;
  float acc[6][4][2] = {};
  for (int k0 = 0; k0 < H; k0 += 16) {
    {
      float4 av = make_float4(0, 0, 0, 0), hv = make_float4(0, 0, 0, 0);
      if (bm + arow < M) {
        av = *(const float4*)(agg + (size_t)(bm + arow) * H + k0 + acol);
        hv = *(const float4*)(hcur + (size_t)(bm + arow) * H + k0 + acol);
      }
      Aa[acol + 0][arow] = av.x; Aa[acol + 1][arow] = av.y;
      Aa[acol + 2][arow] = av.z; Aa[acol + 3][arow] = av.w;
      Ah[acol + 0][arow] = hv.x; Ah[acol + 1][arow] = hv.y;
      Ah[acol + 2][arow] = hv.z; Ah[acol + 3][arow] = hv.w;
    }
#pragma unroll
    for (int t = 0; t < 3; t++) {
      int idx = tid + t * 256;
      int g = idx >> 7;
      int rem = idx & 127;
      int c = rem >> 2;
      int kq = (rem & 3) * 4;
      const float* W = (g < 3) ? W_ih : W_hh;
      int grow = (g % 3) * H + bn + c;
      float4 wv = make_float4(0, 0, 0, 0);
      if (bn + c < H)
        wv = *(const float4*)(W + (size_t)grow * H + k0 + kq);
      Bs[g][kq + 0][c] = wv.x; Bs[g][kq + 1][c] = wv.y;
      Bs[g][kq + 2][c] = wv.z; Bs[g][kq + 3][c] = wv.w;
    }
    __syncthreads();
#pragma unroll
    for (int kk = 0; kk < 16; kk++) {
      float4 a4 = *(const float4*)&Aa[kk][ty * 4];
      float4 h4 = *(const float4*)&Ah[kk][ty * 4];
      float aa[4] = {a4.x, a4.y, a4.z, a4.w};
      float hh[4] = {h4.x, h4.y, h4.z, h4.w};
      float bb[6][2];
#pragma unroll
      for (int g = 0; g < 6; g++) {
        float2 b2 = *(const float2*)&Bs[g][kk][tx * 2];
        bb[g][0] = b2.x; bb[g][1] = b2.y;
      }
#pragma unroll
      for (int i = 0; i < 4; i++)
#pragma unroll
        for (int j = 0; j < 2; j++) {
          acc[0][i][j] = fmaf(aa[i], bb[0][j], acc[0][i][j]);
          acc[1][i][j] = fmaf(aa[i], bb[1][j], acc[1][i][j]);
          acc[2][i][j] = fmaf(aa[i], bb[2][j], acc[2][i][j]);
          acc[3][i][j] = fmaf(hh[i], bb[3][j], acc[3][i][j]);
          acc[4][i][j] = fmaf(hh[i], bb[4][j], acc[4][i][j]);
          acc[5][i][j] = fmaf(hh[i], bb[5][j], acc[5][i][j]);
        }
    }
    __syncthreads();
  }
#pragma unroll
  for (int i = 0; i < 4; i++) {
    int row = bm + ty * 4 + i;
    if (row >= M) continue;
#pragma unroll
    for (int j = 0; j < 2; j++) {
      int cc = bn + tx * 2 + j;
      if (cc >= H) continue;
      float ir = acc[0][i][j] + b_ih[cc];
      float iz = acc[1][i][j] + b_ih[H + cc];
      float inn = acc[2][i][j] + b_ih[2 * H + cc];
      float hr = acc[3][i][j] + b_hh[cc];
      float hz = acc[4][i][j] + b_hh[H + cc];
      float hn = acc[5][i][j] + b_hh[2 * H + cc];
      float r = 1.f / (1.f + expf(-(ir + hr)));
      float z = 1.f / (1.f + expf(-(iz + hz)));
      float nn = tanhf(inn + r * hn);
      float hold = hcur[(size_t)row * H + cc];
      hnew[(size_t)row * H + cc] = (1.f - z) * nn + z * hold;
    }
  }
}

// ---------------- relu + segment max pool ----------------
__global__ void pool_kernel(const float* __restrict__ h, const int* __restrict__ starts,
                            float* __restrict__ pooled) {
  int b = blockIdx.x;
  int s = starts[b], e = starts[b + 1];
  const float4* h4 = (const float4*)h;
  float4* p4 = (float4*)pooled;
  for (int idx = threadIdx.x; idx < H / 4; idx += 256) {
    float4 mx = make_float4(-1e30f, -1e30f, -1e30f, -1e30f);
    for (int n = s; n < e; n++) {
      float4 v = h4[(size_t)n * (H / 4) + idx];
      mx.x = fmaxf(mx.x, v.x); mx.y = fmaxf(mx.y, v.y);
      mx.z = fmaxf(mx.z, v.z); mx.w = fmaxf(mx.w, v.w);
    }
    mx.x = fmaxf(mx.x, 0.f); mx.y = fmaxf(mx.y, 0.f);
    mx.z = fmaxf(mx.z, 0.f); mx.w = fmaxf(mx.w, 0.f);
    p4[b * (H / 4) + idx] = mx;
  }
}

// ---------------- conv1 (1 in-ch) + relu + pool3 ----------------
__global__ void conv1_kernel(const float* __restrict__ in, const float* __restrict__ w,
                             const float* __restrict__ bias, float* __restrict__ outp) {
  __shared__ float sin_[H];
  int b = blockIdx.x;
  for (int j = threadIdx.x; j < H; j += 256) sin_[j] = in[(size_t)b * H + j];
  __syncthreads();
  for (int idx = threadIdx.x; idx < C1_OC * C1_L; idx += 256) {
    int oc = idx / C1_L, t = idx % C1_L;
    float w0 = w[oc * 3], w1 = w[oc * 3 + 1], w2 = w[oc * 3 + 2];
    float bb = bias[oc];
    float best = 0.f;
    int base = t * 3;
#pragma unroll
    for (int p = 0; p < 3; p++) {
      float v = fmaf(sin_[base + p], w0, fmaf(sin_[base + p + 1], w1,
                fmaf(sin_[base + p + 2], w2, bb)));
      best = fmaxf(best, v);
    }
    outp[((size_t)b * C1_OC + oc) * C1_L + t] = best;
  }
}

// ---------------- conv2/conv3 + relu + pool3 (one thread per output) ----------------
__global__ void conv2_kernel(const float* __restrict__ in, const float* __restrict__ w,
                             const float* __restrict__ bias, float* __restrict__ outp) {
  int idx = blockIdx.x * 256 + threadIdx.x;
  if (idx >= NB * C2_OC * C2_L) return;
  int t = idx % C2_L;
  int rem = idx / C2_L;
  int oc = rem % C2_OC;
  int b = rem / C2_OC;
  const float* ip = in + (size_t)b * C1_OC * C1_L;
  const float* wp = w + oc * C1_OC * 3;
  float bb = bias[oc];
  float s0 = bb, s1 = bb, s2 = bb;
  int tc = t * 3;
  for (int ic = 0; ic < C1_OC; ic++) {
    const float* r = ip + ic * C1_L + tc;
    float v0 = r[0], v1 = r[1], v2 = r[2], v3 = r[3], v4 = r[4];
    float w0 = wp[ic * 3], w1 = wp[ic * 3 + 1], w2 = wp[ic * 3 + 2];
    s0 = fmaf(v0, w0, fmaf(v1, w1, fmaf(v2, w2, s0)));
    s1 = fmaf(v1, w0, fmaf(v2, w1, fmaf(v3, w2, s1)));
    s2 = fmaf(v2, w0, fmaf(v3, w1, fmaf(v4, w2, s2)));
  }
  outp[idx] = fmaxf(fmaxf(s0, fmaxf(s1, s2)), 0.f);
}

__global__ void conv3_kernel(const float* __restrict__ in, const float* __restrict__ w,
                             const float* __restrict__ bias, float* __restrict__ outp) {
  int idx = blockIdx.x * 256 + threadIdx.x;
  if (idx >= NB * C3_OC * C3_L) return;
  int t = idx % C3_L;
  int rem = idx / C3_L;
  int oc = rem % C3_OC;
  int b = rem / C3_OC;
  const float* ip = in + (size_t)b * C2_OC * C2_L;
  const float* wp = w + oc * C2_OC * 3;
  float bb = bias[oc];
  float s0 = bb, s1 = bb, s2 = bb;
  int tc = t * 3;
  for (int ic = 0; ic < C2_OC; ic++) {
    const float* r = ip + ic * C2_L + tc;
    float v0 = r[0], v1 = r[1], v2 = r[2], v3 = r[3], v4 = r[4];
    float w0 = wp[ic * 3], w1 = wp[ic * 3 + 1], w2 = wp[ic * 3 + 2];
    s0 = fmaf(v0, w0, fmaf(v1, w1, fmaf(v2, w2, s0)));
    s1 = fmaf(v1, w0, fmaf(v2, w1, fmaf(v3, w2, s1)));
    s2 = fmaf(v2, w0, fmaf(v3, w1, fmaf(v4, w2, s2)));
  }
  outp[idx] = fmaxf(fmaxf(s0, fmaxf(s1, s2)), 0.f);
}

// ---------------- lin1: wave per output ----------------
__global__ void lin1_kernel(const float* __restrict__ x, const float* __restrict__ w,
                            const float* __restrict__ bias, float* __restrict__ outp) {
  int gid = blockIdx.x * 4 + (threadIdx.x >> 6);
  int lane = threadIdx.x & 63;
  int b = gid / LIN1_OUT;
  int o = gid % LIN1_OUT;
  const float* xp = x + (size_t)b * LIN1_IN;
  const float* wp = w + (size_t)o * LIN1_IN;
  float s = 0.f;
  for (int k = lane; k < LIN1_IN; k += 64) s = fmaf(xp[k], wp[k], s);
#pragma unroll
  for (int off = 32; off > 0; off >>= 1) s += __shfl_down(s, off, 64);
  if (lane == 0) outp[b * LIN1_OUT + o] = fmaxf(s + bias[o], 0.f);
}

// ---------------- lin2 ----------------
__global__ void lin2_kernel(const float* __restrict__ x, const float* __restrict__ w,
                            const float* __restrict__ bias, float* __restrict__ outp) {
  int tid = threadIdx.x;
  int b = tid >> 2, o = tid & 3;
  const float* xp = x + b * LIN1_OUT;
  const float* wp = w + o * LIN1_OUT;
  float s = bias[o];
  for (int k = 0; k < LIN1_OUT; k++) s = fmaf(xp[k], wp[k], s);
  outp[b * 4 + o] = fmaxf(s, 0.f);
}

extern "C" void kernel_launch(void* const* d_in, const int* in_sizes, int n_in,
                              void* d_out, int out_size, void* d_ws, size_t ws_size,
                              hipStream_t stream) {
  const int* tokens = (const int*)d_in[0];
  const int* edge_index = (const int*)d_in[1];
  const int* batch = (const int*)d_in[2];
  const float* embed = (const float*)d_in[3];
  const float* W_ggc = (const float*)d_in[4];
  const float* W_ih = (const float*)d_in[5];
  const float* W_hh = (const float*)d_in[6];
  const float* b_ih = (const float*)d_in[7];
  const float* b_hh = (const float*)d_in[8];
  const float* c1w = (const float*)d_in[9];
  const float* c1b = (const float*)d_in[10];
  const float* c2w = (const float*)d_in[11];
  const float* c2b = (const float*)d_in[12];
  const float* c3w = (const float*)d_in[13];
  const float* c3b = (const float*)d_in[14];
  const float* l1w = (const float*)d_in[15];
  const float* l1b = (const float*)d_in[16];
  const float* l2w = (const float*)d_in[17];
  const float* l2b = (const float*)d_in[18];
  float* out = (float*)d_out;

  char* ws = (char*)d_ws;
  size_t off = 0;
  auto alloc = [&](size_t bytes) -> void* {
    void* p = ws + off;
    off = (off + bytes + 255) & ~(size_t)255;
    return p;
  };
  float* buf0 = (float*)alloc(sizeof(float) * (size_t)N_NODES * H);
  float* buf1 = (float*)alloc(sizeof(float) * (size_t)N_NODES * H);
  float* buf2 = (float*)alloc(sizeof(float) * (size_t)N_NODES * H);
  float* pooled = (float*)alloc(sizeof(float) * NB * H);
  float* c1 = (float*)alloc(sizeof(float) * (size_t)NB * C1_OC * C1_L);
  float* c2 = (float*)alloc(sizeof(float) * (size_t)NB * C2_OC * C2_L);
  float* c3 = (float*)alloc(sizeof(float) * (size_t)NB * C3_OC * C3_L);
  float* l1out = (float*)alloc(sizeof(float) * NB * LIN1_OUT);
  int* counts = (int*)alloc(sizeof(int) * (N_NODES + 1));
  int* row_off = (int*)alloc(sizeof(int) * (N_NODES + 1));
  int* cursor = (int*)alloc(sizeof(int) * N_NODES);
  int* csr_src = (int*)alloc(sizeof(int) * N_EDGES);
  int* starts = (int*)alloc(sizeof(int) * (NB + 1));

  const int* e_src = edge_index;
  const int* e_dst = edge_index + N_EDGES;

  hipMemsetAsync(counts, 0, sizeof(int) * (N_NODES + 1), stream);
  hipMemsetAsync(cursor, 0, sizeof(int) * N_NODES, stream);

  embed_kernel<<<N_NODES, 256, 0, stream>>>(tokens, embed, buf0);
  hist_kernel<<<(N_EDGES + 255) / 256, 256, 0, stream>>>(e_dst, counts, N_EDGES);
  scan_kernel<<<1, 1024, 0, stream>>>(counts, row_off, N_NODES);
  scatter_kernel<<<(N_EDGES + 255) / 256, 256, 0, stream>>>(e_src, e_dst, row_off, cursor,
                                                            csr_src, N_EDGES);
  starts_kernel<<<(N_NODES + 255) / 256, 256, 0, stream>>>(batch, starts, N_NODES);

  float* h = buf0;
  float* s1 = buf1;
  float* s2 = buf2;
  dim3 gemm_grid((H + 63) / 64, (N_NODES + 63) / 64);
  dim3 gru_grid((H + 31) / 32, (N_NODES + 63) / 64);
  for (int l = 0; l < LAYERS; l++) {
    gemm_nn_kernel<<<gemm_grid, 256, 0, stream>>>(h, W_ggc + (size_t)l * H * H, s1,
                                                  N_NODES, H, H);
    agg_kernel<<<N_NODES, 256, 0, stream>>>(s1, row_off, csr_src, s2);
    gru_fused_kernel<<<gru_grid, 256, 0, stream>>>(s2, h, W_ih, W_hh, b_ih, b_hh, s1,
                                                   N_NODES);
    float* tmp = h; h = s1; s1 = tmp;
  }

  pool_kernel<<<NB, 256, 0, stream>>>(h, starts, pooled);
  conv1_kernel<<<NB, 256, 0, stream>>>(pooled, c1w, c1b, c1);
  conv2_kernel<<<(NB * C2_OC * C2_L + 255) / 256, 256, 0, stream>>>(c1, c2w, c2b, c2);
  conv3_kernel<<<(NB * C3_OC * C3_L + 255) / 256, 256, 0, stream>>>(c2, c3w, c3b, c3);
  lin1_kernel<<<NB * LIN1_OUT / 4, 256, 0, stream>>>(c3, l1w, l1b, l1out);
  lin2_kernel<<<1, 256, 0, stream>>>(l1out, l2w, l2b, out);
}